// Round 2
// 193.011 us; speedup vs baseline: 1.0037x; 1.0037x over previous
//
#include <hip/hip_runtime.h>
#include <hip/hip_bf16.h>
#include <math.h>

#define B_  2
#define S_  2048
#define D_  1024
#define H_  16
#define DH_ 64
#define M_  (B_ * S_)   // 4096 tokens

typedef __attribute__((ext_vector_type(8))) short bf16x8;  // 8 bf16 (4 VGPRs)
typedef __attribute__((ext_vector_type(4))) float f32x4;   // MFMA C/D frag

__device__ __forceinline__ float fast_exp2(float x) {
  return __builtin_amdgcn_exp2f(x);   // v_exp_f32
}

__device__ __forceinline__ unsigned short f2bf(float f) {
  union { float f; unsigned u; } c; c.f = f;
  unsigned u = c.u;
  return (unsigned short)((u + 0x7FFFu + ((u >> 16) & 1u)) >> 16);  // RNE
}

// pack two floats -> one dword of 2 bf16 via HW cvt (1 VALU instr)
__device__ __forceinline__ unsigned cvtpk(float lo, float hi) {
  unsigned r;
  asm("v_cvt_pk_bf16_f32 %0, %1, %2" : "=v"(r) : "v"(lo), "v"(hi));
  return r;
}

__device__ __forceinline__ float logsig(float x) {
  return fminf(x, 0.f) - log1pf(__expf(-fabsf(x)));   // stable log_sigmoid
}

// ---------------------------------------------------------------------------
// Kernel 0a: hs fp32 [M][D] -> bf16 hsb (streaming, memory-bound)
// ---------------------------------------------------------------------------
__global__ __launch_bounds__(256) void prep_hs(
    const float* __restrict__ hs, unsigned short* __restrict__ hsb)
{
  const int nvec = M_ * D_ / 4;   // 1M float4 groups
  for (int i = blockIdx.x * 256 + threadIdx.x; i < nvec; i += gridDim.x * 256) {
    const float4 v = *(const float4*)&hs[(size_t)i * 4];
    const ushort4 u = {f2bf(v.x), f2bf(v.y), f2bf(v.z), f2bf(v.w)};
    *(ushort4*)&hsb[(size_t)i * 4] = u;
  }
}

// ---------------------------------------------------------------------------
// Kernel 0b: transpose Wq/Wk (fp32 [K][N]) -> bf16 W^T [N][K]
// ---------------------------------------------------------------------------
__global__ __launch_bounds__(256) void prep_w(
    const float* __restrict__ Wq, const float* __restrict__ Wk,
    unsigned short* __restrict__ WqT, unsigned short* __restrict__ WkT)
{
  __shared__ unsigned short T[64][72];
  const int tid = threadIdx.x;
  const int k0 = blockIdx.x * 64;
  const int n0 = blockIdx.y * 64;
  const float* W = blockIdx.z ? Wk : Wq;
  unsigned short* WT = blockIdx.z ? WkT : WqT;

  const int kr = tid >> 2, nc = (tid & 3) * 16;
  #pragma unroll
  for (int i = 0; i < 4; i++) {
    const float4 v = *(const float4*)&W[(size_t)(k0 + kr) * D_ + n0 + nc + i * 4];
    T[nc + i * 4 + 0][kr] = f2bf(v.x);
    T[nc + i * 4 + 1][kr] = f2bf(v.y);
    T[nc + i * 4 + 2][kr] = f2bf(v.z);
    T[nc + i * 4 + 3][kr] = f2bf(v.w);
  }
  __syncthreads();
  const int nr = tid >> 2, kc = (tid & 3) * 16;
  const uint4 a = *(const uint4*)&T[nr][kc];
  const uint4 b = *(const uint4*)&T[nr][kc + 8];
  *(uint4*)&WT[(size_t)(n0 + nr) * D_ + k0 + kc] = a;
  *(uint4*)&WT[(size_t)(n0 + nr) * D_ + k0 + kc + 8] = b;
}

// ---------------------------------------------------------------------------
// Kernel 1: Q = hs@Wq+bq ; K2 = logsig(logsig(Q)+Q+hs@Wk+bk)
//   inputs all bf16 (hsb, WqT, WkT); outputs K2b [M][D], QT [H*64][M]
// Tile 128m x 64n (n-block == one head), BK=64, 4 waves x 2 m-subtiles.
// ---------------------------------------------------------------------------
__global__ __launch_bounds__(256) void proj_kernel(
    const unsigned short* __restrict__ hsb,
    const unsigned short* __restrict__ WqT, const unsigned short* __restrict__ WkT,
    const float* __restrict__ bqv, const float* __restrict__ bkv,
    unsigned short* __restrict__ K2b, unsigned short* __restrict__ QT)
{
  __shared__ unsigned short Ash[128][72];     // hs tile [m][k]
  __shared__ unsigned short Bsh[2][64][72];   // W^T tiles [n][k]

  const int tid  = threadIdx.x;
  const int w    = tid >> 6;
  const int lane = tid & 63;
  const int quad = lane >> 4;
  const int l16  = lane & 15;
  const int m0 = blockIdx.x * 128;
  const int n0 = blockIdx.y * 64;     // = head * 64

  float bqs[4], bks[4];
  #pragma unroll
  for (int nt = 0; nt < 4; nt++) {
    bqs[nt] = bqv[n0 + nt * 16 + l16];
    bks[nt] = bkv[n0 + nt * 16 + l16];
  }

  f32x4 accQ[2][4], accK[2][4];
  #pragma unroll
  for (int st = 0; st < 2; st++)
    #pragma unroll
    for (int nt = 0; nt < 4; nt++) {
      accQ[st][nt] = (f32x4){0.f, 0.f, 0.f, 0.f};
      accK[st][nt] = (f32x4){0.f, 0.f, 0.f, 0.f};
    }

  const int am = tid >> 1, ac = (tid & 1) * 32;   // A: 128 rows x 64 cols
  const int bn = tid >> 2, bc = (tid & 3) * 16;   // B: 64 rows x 64 cols per mat

  for (int k0 = 0; k0 < D_; k0 += 64) {
    // stage A: pure b128 copies (bf16 source)
    {
      const size_t r = (size_t)(m0 + am) * D_ + k0 + ac;
      #pragma unroll
      for (int i = 0; i < 4; i++)
        *(uint4*)&Ash[am][ac + i * 8] = *(const uint4*)&hsb[r + i * 8];
    }
    // stage B (both mats): b128 copies
    {
      const size_t r = (size_t)(n0 + bn) * D_ + k0 + bc;
      *(uint4*)&Bsh[0][bn][bc]     = *(const uint4*)&WqT[r];
      *(uint4*)&Bsh[0][bn][bc + 8] = *(const uint4*)&WqT[r + 8];
      *(uint4*)&Bsh[1][bn][bc]     = *(const uint4*)&WkT[r];
      *(uint4*)&Bsh[1][bn][bc + 8] = *(const uint4*)&WkT[r + 8];
    }
    __syncthreads();

    #pragma unroll
    for (int kk = 0; kk < 2; kk++) {
      bf16x8 af[2];
      af[0] = *(const bf16x8*)&Ash[w * 32 + l16][kk * 32 + quad * 8];
      af[1] = *(const bf16x8*)&Ash[w * 32 + 16 + l16][kk * 32 + quad * 8];
      #pragma unroll
      for (int nt = 0; nt < 4; nt++) {
        const bf16x8 bq = *(const bf16x8*)&Bsh[0][nt * 16 + l16][kk * 32 + quad * 8];
        const bf16x8 bk = *(const bf16x8*)&Bsh[1][nt * 16 + l16][kk * 32 + quad * 8];
        accQ[0][nt] = __builtin_amdgcn_mfma_f32_16x16x32_bf16(af[0], bq, accQ[0][nt], 0, 0, 0);
        accQ[1][nt] = __builtin_amdgcn_mfma_f32_16x16x32_bf16(af[1], bq, accQ[1][nt], 0, 0, 0);
        accK[0][nt] = __builtin_amdgcn_mfma_f32_16x16x32_bf16(af[0], bk, accK[0][nt], 0, 0, 0);
        accK[1][nt] = __builtin_amdgcn_mfma_f32_16x16x32_bf16(af[1], bk, accK[1][nt], 0, 0, 0);
      }
    }
    __syncthreads();
  }

  // epilogue: bias + logsigmoid chain; K2 row-major stores; Q -> LDS transpose
  unsigned short* Qt = &Bsh[0][0][0];   // 64*136 = 8704 shorts <= 9216 avail
  #pragma unroll
  for (int st = 0; st < 2; st++) {
    #pragma unroll
    for (int nt = 0; nt < 4; nt++) {
      float qv[4];
      #pragma unroll
      for (int r = 0; r < 4; r++) {
        const float q  = accQ[st][nt][r] + bqs[nt];
        const float kr = accK[st][nt][r] + bks[nt];
        const float k2 = logsig(logsig(q) + q + kr);
        const int m = m0 + w * 32 + st * 16 + quad * 4 + r;
        K2b[(size_t)m * D_ + n0 + nt * 16 + l16] = f2bf(k2);
        qv[r] = q;
      }
      const ushort4 qu = {f2bf(qv[0]), f2bf(qv[1]), f2bf(qv[2]), f2bf(qv[3])};
      *(ushort4*)&Qt[(nt * 16 + l16) * 136 + w * 32 + st * 16 + quad * 4] = qu;
    }
  }
  __syncthreads();
  {
    const int dr = tid >> 2, mc = (tid & 3) * 32;
    #pragma unroll
    for (int i = 0; i < 4; i++) {
      const uint4 v = *(const uint4*)&Qt[dr * 136 + mc + i * 8];
      *(uint4*)&QT[(size_t)(n0 + dr) * M_ + m0 + mc + i * 8] = v;
    }
  }
}

// ---------------------------------------------------------------------------
// Kernel 2: flash attention, S^T formulation, FIXED-SHIFT softmax.
//   s2 = c2 * sc (exp2 domain); p = exp2(s2 - 12). Shift-invariance makes a
//   constant shift exact; no max-reduce, no rescale.
// Round-2 changes vs the verified round-0 kernel (two-barrier ds_write
// staging structure kept INTACT):
//   - T14 issue-early: K/V tile kt+1's global uint4 loads are issued right
//     after the stage barrier of tile kt and consumed by the next ds_write;
//     HBM/L2 latency hides under the full MFMA+exp phase (grid-limited
//     occupancy of 2 blocks/CU cannot hide it with TLP alone).
//   - Qa staging writes column-swizzled (dcol = dr ^ ((row>>5)<<3)): kills
//     the structural 8-way b16-write bank conflict; read XOR is wave-uniform.
//   - v_cvt_pk_bf16_f32 for P packing (1 instr / 2 elems).
//   - s_setprio(1) around MFMA clusters (T5).
// Block: 128 q x one (b,h); 4 waves x 2 subtiles of 16 q; 64-key tiles.
// ---------------------------------------------------------------------------
__global__ __launch_bounds__(256) void attn_kernel(
    const unsigned short* __restrict__ QT,
    const unsigned short* __restrict__ K2b,
    const int* __restrict__ mask,
    float* __restrict__ out)
{
  __shared__ unsigned short Qa [128][72];  // Q [q][d], col-swizzled
  __shared__ unsigned short K2s[64][72];   // K2 [key][d]
  __shared__ unsigned short Vt [64][72];   // V^T [d][key]
  __shared__ unsigned short Psh[4][16][72];// per-wave P [q16][key64]

  const int tid  = threadIdx.x;
  const int w    = tid >> 6;
  const int lane = tid & 63;
  const int quad = lane >> 4;
  const int l16  = lane & 15;

  const int qt = blockIdx.x;          // 0..15
  const int bh = blockIdx.y;          // 0..31
  const int b = bh >> 4, h = bh & 15;
  const size_t qrow0 = (size_t)b * S_ + (size_t)qt * 128;
  const size_t krow0 = (size_t)b * S_;
  const size_t trow  = (size_t)h * 64;

  // ---- preload K/V tile 0 into registers (T14 issue-early) ----
  const int rr = tid >> 2, cc = (tid & 3) * 16;
  uint4 kreg0, kreg1, vreg0, vreg1;
  {
    const size_t kaddr = (krow0 + rr) * D_ + trow + cc;
    kreg0 = *(const uint4*)&K2b[kaddr];
    kreg1 = *(const uint4*)&K2b[kaddr + 8];
    const size_t vaddr = (trow + rr) * M_ + krow0 + cc;
    vreg0 = *(const uint4*)&QT[vaddr];
    vreg1 = *(const uint4*)&QT[vaddr + 8];
  }

  // ---- stage Qa [q][d] from QT (once per block), swizzled columns ----
  {
    const int dr = tid >> 2, qc = (tid & 3) * 32;
    const int dcol = dr ^ ((tid & 3) << 3);   // (row>>5) == tid&3 for all rows written
    #pragma unroll
    for (int i = 0; i < 4; i++) {
      const uint4 v = *(const uint4*)&QT[(trow + dr) * M_ + qrow0 + qc + i * 8];
      const unsigned short* p = (const unsigned short*)&v;
      #pragma unroll
      for (int j = 0; j < 8; j++) Qa[qc + i * 8 + j][dcol] = p[j];
    }
  }
  __syncthreads();

  // Q fragments (B-operand): read with wave-uniform un-swizzle XOR (free)
  bf16x8 qfrag[2][2];
  #pragma unroll
  for (int st = 0; st < 2; st++)
    #pragma unroll
    for (int kk = 0; kk < 2; kk++)
      qfrag[st][kk] =
          *(const bf16x8*)&Qa[w * 32 + st * 16 + l16][(kk * 32 + quad * 8) ^ (w << 3)];

  // c2 = -(1/8)*log2(e)*msk ; fixed shift of 12 in exp2 domain
  float c2[2], rl[2] = {0.f, 0.f};
  #pragma unroll
  for (int st = 0; st < 2; st++)
    c2[st] = (mask[qrow0 + w * 32 + st * 16 + l16] != 0) ? -0.18033688f : 0.f;

  f32x4 Ot[2][4];
  #pragma unroll
  for (int st = 0; st < 2; st++)
    #pragma unroll
    for (int dt = 0; dt < 4; dt++) Ot[st][dt] = (f32x4){0.f, 0.f, 0.f, 0.f};

  for (int kt = 0; kt < S_ / 64; kt++) {
    __syncthreads();   // all waves done reading LDS of tile kt-1
    // stage tile kt from registers (vmcnt wait auto-inserted for the loads)
    *(uint4*)&K2s[rr][cc]     = kreg0;
    *(uint4*)&K2s[rr][cc + 8] = kreg1;
    *(uint4*)&Vt [rr][cc]     = vreg0;
    *(uint4*)&Vt [rr][cc + 8] = vreg1;
    __syncthreads();   // staged

    // T14: issue tile kt+1's global loads NOW; they drain during compute
    if (kt + 1 < S_ / 64) {
      const size_t kaddr = (krow0 + (kt + 1) * 64 + rr) * D_ + trow + cc;
      kreg0 = *(const uint4*)&K2b[kaddr];
      kreg1 = *(const uint4*)&K2b[kaddr + 8];
      const size_t vaddr = (trow + rr) * M_ + krow0 + (kt + 1) * 64 + cc;
      vreg0 = *(const uint4*)&QT[vaddr];
      vreg1 = *(const uint4*)&QT[vaddr + 8];
    }

    bf16x8 k2f[4][2], vf[4][2];
    #pragma unroll
    for (int nt = 0; nt < 4; nt++)
      #pragma unroll
      for (int kk = 0; kk < 2; kk++) {
        k2f[nt][kk] = *(const bf16x8*)&K2s[nt * 16 + l16][kk * 32 + quad * 8];
        vf[nt][kk]  = *(const bf16x8*)&Vt [nt * 16 + l16][kk * 32 + quad * 8];
      }

    #pragma unroll
    for (int st = 0; st < 2; st++) {
      f32x4 sc[4];
      #pragma unroll
      for (int nt = 0; nt < 4; nt++) sc[nt] = (f32x4){0.f, 0.f, 0.f, 0.f};
      __builtin_amdgcn_s_setprio(1);
      #pragma unroll
      for (int kk = 0; kk < 2; kk++)
        #pragma unroll
        for (int nt = 0; nt < 4; nt++)
          sc[nt] = __builtin_amdgcn_mfma_f32_16x16x32_bf16(k2f[nt][kk], qfrag[st][kk], sc[nt], 0, 0, 0);
      __builtin_amdgcn_s_setprio(0);

      // p = exp2(c2*sc - 12); accumulate row-sum; pack pairs -> Psh
      #pragma unroll
      for (int nt = 0; nt < 4; nt++) {
        float p0 = fast_exp2(fmaf(sc[nt][0], c2[st], -12.f));
        float p1 = fast_exp2(fmaf(sc[nt][1], c2[st], -12.f));
        float p2 = fast_exp2(fmaf(sc[nt][2], c2[st], -12.f));
        float p3 = fast_exp2(fmaf(sc[nt][3], c2[st], -12.f));
        rl[st] += (p0 + p1) + (p2 + p3);
        const uint2 pk = {cvtpk(p0, p1), cvtpk(p2, p3)};
        *(uint2*)&Psh[w][l16][nt * 16 + quad * 4] = pk;
      }

      #pragma unroll
      for (int kk = 0; kk < 2; kk++) {
        const bf16x8 pf = *(const bf16x8*)&Psh[w][l16][kk * 32 + quad * 8];
        __builtin_amdgcn_s_setprio(1);
        #pragma unroll
        for (int dt = 0; dt < 4; dt++)
          Ot[st][dt] = __builtin_amdgcn_mfma_f32_16x16x32_bf16(vf[dt][kk], pf, Ot[st][dt], 0, 0, 0);
        __builtin_amdgcn_s_setprio(0);
      }
    }
  }

  // final row-sum across quads, then write O / l
  #pragma unroll
  for (int st = 0; st < 2; st++) {
    float li = rl[st];
    li += __shfl_xor(li, 16);
    li += __shfl_xor(li, 32);
    const float inv = 1.f / fmaxf(li, 1e-35f);
    const size_t orow = (qrow0 + w * 32 + st * 16 + l16) * D_ + trow;
    #pragma unroll
    for (int dt = 0; dt < 4; dt++) {
      const float4 o = {Ot[st][dt][0] * inv, Ot[st][dt][1] * inv,
                        Ot[st][dt][2] * inv, Ot[st][dt][3] * inv};
      *(float4*)&out[orow + dt * 16 + quad * 4] = o;
    }
  }
}

extern "C" void kernel_launch(void* const* d_in, const int* in_sizes, int n_in,
                              void* d_out, int out_size, void* d_ws, size_t ws_size,
                              hipStream_t stream) {
  const float* hs  = (const float*)d_in[0];
  const int*   msk = (const int*)d_in[1];
  const float* Wq  = (const float*)d_in[2];
  const float* bq  = (const float*)d_in[3];
  const float* Wk  = (const float*)d_in[4];
  const float* bk  = (const float*)d_in[5];
  float* out = (float*)d_out;

  unsigned short* QT  = (unsigned short*)d_ws;             // [H*64][M_]  8 MB
  unsigned short* K2b = QT  + (size_t)D_ * M_;             // [M_][D_]    8 MB
  unsigned short* WqT = K2b + (size_t)M_ * D_;             // [D_][D_]    2 MB
  unsigned short* WkT = WqT + (size_t)D_ * D_;             // [D_][D_]    2 MB
  unsigned short* hsb = WkT + (size_t)D_ * D_;             // [M_][D_]    8 MB

  prep_hs<<<1024, 256, 0, stream>>>(hs, hsb);
  prep_w<<<dim3(D_ / 64, D_ / 64, 2), 256, 0, stream>>>(Wq, Wk, WqT, WkT);
  proj_kernel<<<dim3(M_ / 128, D_ / 64), 256, 0, stream>>>(hsb, WqT, WkT, bq, bk, K2b, QT);
  attn_kernel<<<dim3(S_ / 128, B_ * H_), 256, 0, stream>>>(QT, K2b, msk, out);
}

// Round 3
// 192.247 us; speedup vs baseline: 1.0077x; 1.0040x over previous
//
#include <hip/hip_runtime.h>
#include <hip/hip_bf16.h>
#include <math.h>

#define B_  2
#define S_  2048
#define D_  1024
#define H_  16
#define DH_ 64
#define M_  (B_ * S_)   // 4096 tokens

typedef __attribute__((ext_vector_type(8))) short bf16x8;  // 8 bf16 (4 VGPRs)
typedef __attribute__((ext_vector_type(4))) float f32x4;   // MFMA C/D frag

__device__ __forceinline__ float fast_exp2(float x) {
  return __builtin_amdgcn_exp2f(x);   // v_exp_f32
}

__device__ __forceinline__ unsigned short f2bf(float f) {
  union { float f; unsigned u; } c; c.f = f;
  unsigned u = c.u;
  return (unsigned short)((u + 0x7FFFu + ((u >> 16) & 1u)) >> 16);  // RNE
}

// pack two floats -> one dword of 2 bf16 via HW cvt (1 VALU instr)
__device__ __forceinline__ unsigned cvtpk(float lo, float hi) {
  unsigned r;
  asm("v_cvt_pk_bf16_f32 %0, %1, %2" : "=v"(r) : "v"(lo), "v"(hi));
  return r;
}

__device__ __forceinline__ float logsig(float x) {
  // stable log_sigmoid; __logf ok: e in (0,1], result feeds bf16 anyway
  const float e = __expf(-fabsf(x));
  return fminf(x, 0.f) - __logf(1.f + e);
}

// ---------------------------------------------------------------------------
// Kernel 0a: hs fp32 [M][D] -> bf16 hsb (streaming, memory-bound)
// ---------------------------------------------------------------------------
__global__ __launch_bounds__(256) void prep_hs(
    const float* __restrict__ hs, unsigned short* __restrict__ hsb)
{
  const int nvec = M_ * D_ / 4;   // 1M float4 groups
  for (int i = blockIdx.x * 256 + threadIdx.x; i < nvec; i += gridDim.x * 256) {
    const float4 v = *(const float4*)&hs[(size_t)i * 4];
    const ushort4 u = {f2bf(v.x), f2bf(v.y), f2bf(v.z), f2bf(v.w)};
    *(ushort4*)&hsb[(size_t)i * 4] = u;
  }
}

// ---------------------------------------------------------------------------
// Kernel 0b: transpose Wq/Wk (fp32 [K][N]) -> bf16 W^T [N][K]
// ---------------------------------------------------------------------------
__global__ __launch_bounds__(256) void prep_w(
    const float* __restrict__ Wq, const float* __restrict__ Wk,
    unsigned short* __restrict__ WqT, unsigned short* __restrict__ WkT)
{
  __shared__ unsigned short T[64][72];
  const int tid = threadIdx.x;
  const int k0 = blockIdx.x * 64;
  const int n0 = blockIdx.y * 64;
  const float* W = blockIdx.z ? Wk : Wq;
  unsigned short* WT = blockIdx.z ? WkT : WqT;

  const int kr = tid >> 2, nc = (tid & 3) * 16;
  #pragma unroll
  for (int i = 0; i < 4; i++) {
    const float4 v = *(const float4*)&W[(size_t)(k0 + kr) * D_ + n0 + nc + i * 4];
    T[nc + i * 4 + 0][kr] = f2bf(v.x);
    T[nc + i * 4 + 1][kr] = f2bf(v.y);
    T[nc + i * 4 + 2][kr] = f2bf(v.z);
    T[nc + i * 4 + 3][kr] = f2bf(v.w);
  }
  __syncthreads();
  const int nr = tid >> 2, kc = (tid & 3) * 16;
  const uint4 a = *(const uint4*)&T[nr][kc];
  const uint4 b = *(const uint4*)&T[nr][kc + 8];
  *(uint4*)&WT[(size_t)(n0 + nr) * D_ + k0 + kc] = a;
  *(uint4*)&WT[(size_t)(n0 + nr) * D_ + k0 + kc + 8] = b;
}

// ---------------------------------------------------------------------------
// Kernel 1: Q = hs@Wq+bq ; K2 = logsig(logsig(Q)+Q+hs@Wk+bk)
//   inputs all bf16 (hsb, WqT, WkT); outputs K2b [M][D], QT [H*64][M]
// Tile 128m x 64n (n-block == one head), BK=64, 4 waves x 2 m-subtiles.
// Round-3: T14 issue-early/write-late staging — tile kt+1's global loads are
// issued right after the stage barrier of tile kt and consumed by the next
// ds_write. The L2/L3 latency (previously naked between the two barriers,
// x16 K-iters, at only 2 waves/SIMD) now hides under ds_read+MFMA compute.
// ---------------------------------------------------------------------------
__global__ __launch_bounds__(256) void proj_kernel(
    const unsigned short* __restrict__ hsb,
    const unsigned short* __restrict__ WqT, const unsigned short* __restrict__ WkT,
    const float* __restrict__ bqv, const float* __restrict__ bkv,
    unsigned short* __restrict__ K2b, unsigned short* __restrict__ QT)
{
  __shared__ unsigned short Ash[128][72];     // hs tile [m][k]
  __shared__ unsigned short Bsh[2][64][72];   // W^T tiles [n][k]

  const int tid  = threadIdx.x;
  const int w    = tid >> 6;
  const int lane = tid & 63;
  const int quad = lane >> 4;
  const int l16  = lane & 15;
  const int m0 = blockIdx.x * 128;
  const int n0 = blockIdx.y * 64;     // = head * 64

  float bqs[4], bks[4];
  #pragma unroll
  for (int nt = 0; nt < 4; nt++) {
    bqs[nt] = bqv[n0 + nt * 16 + l16];
    bks[nt] = bkv[n0 + nt * 16 + l16];
  }

  f32x4 accQ[2][4], accK[2][4];
  #pragma unroll
  for (int st = 0; st < 2; st++)
    #pragma unroll
    for (int nt = 0; nt < 4; nt++) {
      accQ[st][nt] = (f32x4){0.f, 0.f, 0.f, 0.f};
      accK[st][nt] = (f32x4){0.f, 0.f, 0.f, 0.f};
    }

  const int am = tid >> 1, ac = (tid & 1) * 32;   // A: 128 rows x 64 cols
  const int bn = tid >> 2, bc = (tid & 3) * 16;   // B: 64 rows x 64 cols per mat

  // ---- preload K-tile 0 into registers (T14 issue-early) ----
  uint4 Ar[4], BqA, BqB, BkA, BkB;
  {
    const size_t ra = (size_t)(m0 + am) * D_ + ac;
    #pragma unroll
    for (int i = 0; i < 4; i++) Ar[i] = *(const uint4*)&hsb[ra + i * 8];
    const size_t rb = (size_t)(n0 + bn) * D_ + bc;
    BqA = *(const uint4*)&WqT[rb];  BqB = *(const uint4*)&WqT[rb + 8];
    BkA = *(const uint4*)&WkT[rb];  BkB = *(const uint4*)&WkT[rb + 8];
  }

  for (int k0 = 0; k0 < D_; k0 += 64) {
    if (k0) __syncthreads();   // all waves done reading the previous tile
    // stage tile k0 from registers (vmcnt wait auto-inserted)
    #pragma unroll
    for (int i = 0; i < 4; i++)
      *(uint4*)&Ash[am][ac + i * 8] = Ar[i];
    *(uint4*)&Bsh[0][bn][bc]     = BqA;
    *(uint4*)&Bsh[0][bn][bc + 8] = BqB;
    *(uint4*)&Bsh[1][bn][bc]     = BkA;
    *(uint4*)&Bsh[1][bn][bc + 8] = BkB;
    __syncthreads();           // staged

    // issue tile k0+64's global loads NOW; they drain during compute
    if (k0 + 64 < D_) {
      const size_t ra = (size_t)(m0 + am) * D_ + (k0 + 64) + ac;
      #pragma unroll
      for (int i = 0; i < 4; i++) Ar[i] = *(const uint4*)&hsb[ra + i * 8];
      const size_t rb = (size_t)(n0 + bn) * D_ + (k0 + 64) + bc;
      BqA = *(const uint4*)&WqT[rb];  BqB = *(const uint4*)&WqT[rb + 8];
      BkA = *(const uint4*)&WkT[rb];  BkB = *(const uint4*)&WkT[rb + 8];
    }

    #pragma unroll
    for (int kk = 0; kk < 2; kk++) {
      bf16x8 af[2];
      af[0] = *(const bf16x8*)&Ash[w * 32 + l16][kk * 32 + quad * 8];
      af[1] = *(const bf16x8*)&Ash[w * 32 + 16 + l16][kk * 32 + quad * 8];
      #pragma unroll
      for (int nt = 0; nt < 4; nt++) {
        const bf16x8 bq = *(const bf16x8*)&Bsh[0][nt * 16 + l16][kk * 32 + quad * 8];
        const bf16x8 bk = *(const bf16x8*)&Bsh[1][nt * 16 + l16][kk * 32 + quad * 8];
        accQ[0][nt] = __builtin_amdgcn_mfma_f32_16x16x32_bf16(af[0], bq, accQ[0][nt], 0, 0, 0);
        accQ[1][nt] = __builtin_amdgcn_mfma_f32_16x16x32_bf16(af[1], bq, accQ[1][nt], 0, 0, 0);
        accK[0][nt] = __builtin_amdgcn_mfma_f32_16x16x32_bf16(af[0], bk, accK[0][nt], 0, 0, 0);
        accK[1][nt] = __builtin_amdgcn_mfma_f32_16x16x32_bf16(af[1], bk, accK[1][nt], 0, 0, 0);
      }
    }
  }
  __syncthreads();   // protect epilogue's reuse of Bsh as Qt

  // epilogue: bias + logsigmoid chain; K2 row-major stores; Q -> LDS transpose
  unsigned short* Qt = &Bsh[0][0][0];   // 64*136 = 8704 shorts <= 9216 avail
  #pragma unroll
  for (int st = 0; st < 2; st++) {
    #pragma unroll
    for (int nt = 0; nt < 4; nt++) {
      float qv[4];
      #pragma unroll
      for (int r = 0; r < 4; r++) {
        const float q  = accQ[st][nt][r] + bqs[nt];
        const float kr = accK[st][nt][r] + bks[nt];
        const float k2 = logsig(logsig(q) + q + kr);
        const int m = m0 + w * 32 + st * 16 + quad * 4 + r;
        K2b[(size_t)m * D_ + n0 + nt * 16 + l16] = f2bf(k2);
        qv[r] = q;
      }
      const ushort4 qu = {f2bf(qv[0]), f2bf(qv[1]), f2bf(qv[2]), f2bf(qv[3])};
      *(ushort4*)&Qt[(nt * 16 + l16) * 136 + w * 32 + st * 16 + quad * 4] = qu;
    }
  }
  __syncthreads();
  {
    const int dr = tid >> 2, mc = (tid & 3) * 32;
    #pragma unroll
    for (int i = 0; i < 4; i++) {
      const uint4 v = *(const uint4*)&Qt[dr * 136 + mc + i * 8];
      *(uint4*)&QT[(size_t)(n0 + dr) * M_ + m0 + mc + i * 8] = v;
    }
  }
}

// ---------------------------------------------------------------------------
// Kernel 2: flash attention, S^T formulation, FIXED-SHIFT softmax.
//   s2 = c2 * sc (exp2 domain); p = exp2(s2 - 12). Shift-invariance makes a
//   constant shift exact; no max-reduce, no rescale.
//   (unchanged from round 2 — verified passing)
// ---------------------------------------------------------------------------
__global__ __launch_bounds__(256) void attn_kernel(
    const unsigned short* __restrict__ QT,
    const unsigned short* __restrict__ K2b,
    const int* __restrict__ mask,
    float* __restrict__ out)
{
  __shared__ unsigned short Qa [128][72];  // Q [q][d], col-swizzled
  __shared__ unsigned short K2s[64][72];   // K2 [key][d]
  __shared__ unsigned short Vt [64][72];   // V^T [d][key]
  __shared__ unsigned short Psh[4][16][72];// per-wave P [q16][key64]

  const int tid  = threadIdx.x;
  const int w    = tid >> 6;
  const int lane = tid & 63;
  const int quad = lane >> 4;
  const int l16  = lane & 15;

  const int qt = blockIdx.x;          // 0..15
  const int bh = blockIdx.y;          // 0..31
  const int b = bh >> 4, h = bh & 15;
  const size_t qrow0 = (size_t)b * S_ + (size_t)qt * 128;
  const size_t krow0 = (size_t)b * S_;
  const size_t trow  = (size_t)h * 64;

  // ---- preload K/V tile 0 into registers (T14 issue-early) ----
  const int rr = tid >> 2, cc = (tid & 3) * 16;
  uint4 kreg0, kreg1, vreg0, vreg1;
  {
    const size_t kaddr = (krow0 + rr) * D_ + trow + cc;
    kreg0 = *(const uint4*)&K2b[kaddr];
    kreg1 = *(const uint4*)&K2b[kaddr + 8];
    const size_t vaddr = (trow + rr) * M_ + krow0 + cc;
    vreg0 = *(const uint4*)&QT[vaddr];
    vreg1 = *(const uint4*)&QT[vaddr + 8];
  }

  // ---- stage Qa [q][d] from QT (once per block), swizzled columns ----
  {
    const int dr = tid >> 2, qc = (tid & 3) * 32;
    const int dcol = dr ^ ((tid & 3) << 3);   // (row>>5) == tid&3 for all rows written
    #pragma unroll
    for (int i = 0; i < 4; i++) {
      const uint4 v = *(const uint4*)&QT[(trow + dr) * M_ + qrow0 + qc + i * 8];
      const unsigned short* p = (const unsigned short*)&v;
      #pragma unroll
      for (int j = 0; j < 8; j++) Qa[qc + i * 8 + j][dcol] = p[j];
    }
  }
  __syncthreads();

  // Q fragments (B-operand): read with wave-uniform un-swizzle XOR (free)
  bf16x8 qfrag[2][2];
  #pragma unroll
  for (int st = 0; st < 2; st++)
    #pragma unroll
    for (int kk = 0; kk < 2; kk++)
      qfrag[st][kk] =
          *(const bf16x8*)&Qa[w * 32 + st * 16 + l16][(kk * 32 + quad * 8) ^ (w << 3)];

  // c2 = -(1/8)*log2(e)*msk ; fixed shift of 12 in exp2 domain
  float c2[2], rl[2] = {0.f, 0.f};
  #pragma unroll
  for (int st = 0; st < 2; st++)
    c2[st] = (mask[qrow0 + w * 32 + st * 16 + l16] != 0) ? -0.18033688f : 0.f;

  f32x4 Ot[2][4];
  #pragma unroll
  for (int st = 0; st < 2; st++)
    #pragma unroll
    for (int dt = 0; dt < 4; dt++) Ot[st][dt] = (f32x4){0.f, 0.f, 0.f, 0.f};

  for (int kt = 0; kt < S_ / 64; kt++) {
    __syncthreads();   // all waves done reading LDS of tile kt-1
    // stage tile kt from registers (vmcnt wait auto-inserted for the loads)
    *(uint4*)&K2s[rr][cc]     = kreg0;
    *(uint4*)&K2s[rr][cc + 8] = kreg1;
    *(uint4*)&Vt [rr][cc]     = vreg0;
    *(uint4*)&Vt [rr][cc + 8] = vreg1;
    __syncthreads();   // staged

    // T14: issue tile kt+1's global loads NOW; they drain during compute
    if (kt + 1 < S_ / 64) {
      const size_t kaddr = (krow0 + (kt + 1) * 64 + rr) * D_ + trow + cc;
      kreg0 = *(const uint4*)&K2b[kaddr];
      kreg1 = *(const uint4*)&K2b[kaddr + 8];
      const size_t vaddr = (trow + rr) * M_ + krow0 + (kt + 1) * 64 + cc;
      vreg0 = *(const uint4*)&QT[vaddr];
      vreg1 = *(const uint4*)&QT[vaddr + 8];
    }

    bf16x8 k2f[4][2], vf[4][2];
    #pragma unroll
    for (int nt = 0; nt < 4; nt++)
      #pragma unroll
      for (int kk = 0; kk < 2; kk++) {
        k2f[nt][kk] = *(const bf16x8*)&K2s[nt * 16 + l16][kk * 32 + quad * 8];
        vf[nt][kk]  = *(const bf16x8*)&Vt [nt * 16 + l16][kk * 32 + quad * 8];
      }

    #pragma unroll
    for (int st = 0; st < 2; st++) {
      f32x4 sc[4];
      #pragma unroll
      for (int nt = 0; nt < 4; nt++) sc[nt] = (f32x4){0.f, 0.f, 0.f, 0.f};
      __builtin_amdgcn_s_setprio(1);
      #pragma unroll
      for (int kk = 0; kk < 2; kk++)
        #pragma unroll
        for (int nt = 0; nt < 4; nt++)
          sc[nt] = __builtin_amdgcn_mfma_f32_16x16x32_bf16(k2f[nt][kk], qfrag[st][kk], sc[nt], 0, 0, 0);
      __builtin_amdgcn_s_setprio(0);

      // p = exp2(c2*sc - 12); accumulate row-sum; pack pairs -> Psh
      #pragma unroll
      for (int nt = 0; nt < 4; nt++) {
        float p0 = fast_exp2(fmaf(sc[nt][0], c2[st], -12.f));
        float p1 = fast_exp2(fmaf(sc[nt][1], c2[st], -12.f));
        float p2 = fast_exp2(fmaf(sc[nt][2], c2[st], -12.f));
        float p3 = fast_exp2(fmaf(sc[nt][3], c2[st], -12.f));
        rl[st] += (p0 + p1) + (p2 + p3);
        const uint2 pk = {cvtpk(p0, p1), cvtpk(p2, p3)};
        *(uint2*)&Psh[w][l16][nt * 16 + quad * 4] = pk;
      }

      #pragma unroll
      for (int kk = 0; kk < 2; kk++) {
        const bf16x8 pf = *(const bf16x8*)&Psh[w][l16][kk * 32 + quad * 8];
        __builtin_amdgcn_s_setprio(1);
        #pragma unroll
        for (int dt = 0; dt < 4; dt++)
          Ot[st][dt] = __builtin_amdgcn_mfma_f32_16x16x32_bf16(vf[dt][kk], pf, Ot[st][dt], 0, 0, 0);
        __builtin_amdgcn_s_setprio(0);
      }
    }
  }

  // final row-sum across quads, then write O / l
  #pragma unroll
  for (int st = 0; st < 2; st++) {
    float li = rl[st];
    li += __shfl_xor(li, 16);
    li += __shfl_xor(li, 32);
    const float inv = 1.f / fmaxf(li, 1e-35f);
    const size_t orow = (qrow0 + w * 32 + st * 16 + l16) * D_ + trow;
    #pragma unroll
    for (int dt = 0; dt < 4; dt++) {
      const float4 o = {Ot[st][dt][0] * inv, Ot[st][dt][1] * inv,
                        Ot[st][dt][2] * inv, Ot[st][dt][3] * inv};
      *(float4*)&out[orow + dt * 16 + quad * 4] = o;
    }
  }
}

extern "C" void kernel_launch(void* const* d_in, const int* in_sizes, int n_in,
                              void* d_out, int out_size, void* d_ws, size_t ws_size,
                              hipStream_t stream) {
  const float* hs  = (const float*)d_in[0];
  const int*   msk = (const int*)d_in[1];
  const float* Wq  = (const float*)d_in[2];
  const float* bq  = (const float*)d_in[3];
  const float* Wk  = (const float*)d_in[4];
  const float* bk  = (const float*)d_in[5];
  float* out = (float*)d_out;

  unsigned short* QT  = (unsigned short*)d_ws;             // [H*64][M_]  8 MB
  unsigned short* K2b = QT  + (size_t)D_ * M_;             // [M_][D_]    8 MB
  unsigned short* WqT = K2b + (size_t)M_ * D_;             // [D_][D_]    2 MB
  unsigned short* WkT = WqT + (size_t)D_ * D_;             // [D_][D_]    2 MB
  unsigned short* hsb = WkT + (size_t)D_ * D_;             // [M_][D_]    8 MB

  prep_hs<<<1024, 256, 0, stream>>>(hs, hsb);
  prep_w<<<dim3(D_ / 64, D_ / 64, 2), 256, 0, stream>>>(Wq, Wk, WqT, WkT);
  proj_kernel<<<dim3(M_ / 128, D_ / 64), 256, 0, stream>>>(hsb, WqT, WkT, bq, bk, K2b, QT);
  attn_kernel<<<dim3(S_ / 128, B_ * H_), 256, 0, stream>>>(QT, K2b, msk, out);
}